// Round 3
// baseline (285.635 us; speedup 1.0000x reference)
//
#include <hip/hip_runtime.h>

#define B_SZ   32
#define LEN    2048
#define DIM    256
#define NST    64
#define OUTD   256
#define CHUNK  64
#define NCHUNK (LEN / CHUNK)     // 32
#define ROWS   (B_SZ * LEN)      // 65536

// ws layout (float offsets)
#define OFF_AT   0               // A_tilde [64][64]
#define OFF_P64  4096            // A_tilde^64 [64][64]
#define OFF_MINV 8192            // Minv [64][64]
#define OFF_CP   12288           // CP[o][n] = 0.1*(C@Minv), [256][64]
#define OFF_S    28672           // chunk-final states [B][NCHUNK][64]
#define OFF_INST 94208           // chunk carry-in states [B][NCHUNK][64]
#define OFF_V    159744          // v = x @ B^T [ROWS][64]
#define WS_FLOATS (OFF_V + (size_t)ROWS * 64)   // 4,354,048 floats = 16.6 MiB

// row-swizzle key for [*][64] LDS tiles read both per-lane and as k-float4
#define KEYR(row) ((((row) >> 3) ^ (row)) & 7)

// ---------------------------------------------------------------------------
__device__ __forceinline__ void gload16(const float* gp, float* lds_base,
                                        int lane_off_f) {
#if __has_builtin(__builtin_amdgcn_global_load_lds)
  (void)lane_off_f;
  __builtin_amdgcn_global_load_lds(
      (const __attribute__((address_space(1))) unsigned int*)gp,
      (__attribute__((address_space(3))) unsigned int*)lds_base, 16, 0, 0);
#else
  float4 tmp = *(const float4*)gp;
  *(float4*)(lds_base + lane_off_f) = tmp;
#endif
}

// dst = a @ b, [64][68] LDS tiles, 256 threads, 4x4 reg tiles. Barrier at end.
__device__ __forceinline__ void mm64(float* dst, const float* a, const float* b,
                                     int t) {
  const int r0 = 4 * (t >> 4), c0 = 4 * (t & 15);
  float acc[4][4] = {};
  for (int k = 0; k < 64; ++k) {
    float4 bv = *(const float4*)(b + k * 68 + c0);
#pragma unroll
    for (int i = 0; i < 4; ++i) {
      float av = a[(r0 + i) * 68 + k];
      acc[i][0] = fmaf(av, bv.x, acc[i][0]);
      acc[i][1] = fmaf(av, bv.y, acc[i][1]);
      acc[i][2] = fmaf(av, bv.z, acc[i][2]);
      acc[i][3] = fmaf(av, bv.w, acc[i][3]);
    }
  }
  __syncthreads();
#pragma unroll
  for (int i = 0; i < 4; ++i)
    *(float4*)(dst + (r0 + i) * 68 + c0) =
        make_float4(acc[i][0], acc[i][1], acc[i][2], acc[i][3]);
  __syncthreads();
}

// ---------------------------------------------------------------------------
// K_A fused: block 0 = GJ inverse only (AT, Minv -> ws).
// Blocks 1..512 = v-GEMM: 128 rows/block, B-stationary in LDS (swizzled),
// x streamed global->regs, zero in-loop barriers.
// ---------------------------------------------------------------------------
__global__ __launch_bounds__(256) void k_fused0(const float* __restrict__ A,
                                                const float* __restrict__ Bm,
                                                const float* __restrict__ x,
                                                float* __restrict__ ws) {
  __shared__ __align__(16) float sh[16384];    // 64 KB
  const int t = threadIdx.x;

  if (blockIdx.x == 0) {
    float* rbM = sh;            // [2][64]
    float* rbI = sh + 128;      // [2][64]
    float* cb  = sh + 256;      // [2][64]
    const int tc = t & 63;
    const int tr = t >> 6;
    float M[16], Iv[16];
#pragma unroll
    for (int i = 0; i < 16; ++i) {
      int r = 16 * tr + i;
      M[i] = 0.05f * A[r * 64 + tc] + (r == tc ? 1.0f : 0.0f);
      Iv[i] = (r == tc) ? 1.0f : 0.0f;
    }
    if (tr == 0) { rbM[tc] = M[0]; rbI[tc] = Iv[0]; }
    if (tc == 0)
      for (int i = 0; i < 16; ++i) cb[16 * tr + i] = M[i];
    __syncthreads();
#pragma unroll
    for (int k = 0; k < 64; ++k) {
      const int cur = (k & 1) * 64, nxt = ((k + 1) & 1) * 64;
      float rinv = 1.0f / rbM[cur + k];
      float rM = rbM[cur + tc] * rinv;
      float rI = rbI[cur + tc] * rinv;
#pragma unroll
      for (int i = 0; i < 16; ++i) {
        int r = 16 * tr + i;
        if (r == k) { M[i] = rM; Iv[i] = rI; }
        else {
          float f = cb[cur + r];
          M[i] = fmaf(-f, rM, M[i]);
          Iv[i] = fmaf(-f, rI, Iv[i]);
        }
      }
      if (k < 63) {
        if (tr == ((k + 1) >> 4)) {
          rbM[nxt + tc] = M[(k + 1) & 15];
          rbI[nxt + tc] = Iv[(k + 1) & 15];
        }
        if (tc == k + 1)
          for (int i = 0; i < 16; ++i) cb[nxt + 16 * tr + i] = M[i];
      }
      __syncthreads();
    }
#pragma unroll
    for (int i = 0; i < 16; ++i) {
      int r = 16 * tr + i;
      ws[OFF_AT + r * 64 + tc] = 2.0f * Iv[i] - (r == tc ? 1.0f : 0.0f);
      ws[OFF_MINV + r * 64 + tc] = Iv[i];
    }
  } else {
    // ---- v-GEMM ----
    float* Bl = sh;                       // [64][256] swizzled by KEYB(m)=(m>>2)&7
    const int w = t >> 6, lane = t & 63;
    // stage B once: chunk m (1 row, 1KB); wave w -> rows 16w..16w+15
#pragma unroll
    for (int c2 = 0; c2 < 16; ++c2) {
      int m = 16 * w + c2;
      const float* gp = Bm + (size_t)m * 256 + 4 * (lane ^ ((m >> 2) & 7));
      gload16(gp, Bl + m * 256, lane * 4);
    }
    __syncthreads();

    const int band = w >> 1, half = w & 1;
    const int rg = lane >> 3, mg = lane & 7;
    const int rowbase = ((int)blockIdx.x - 1) * 128 + band * 64;
    const int m0 = half * 32 + mg * 4;
    const float* xw = x + (size_t)rowbase * 256;

    float acc[8][4] = {};
    float4 aA[8], aB[8];
#pragma unroll
    for (int i = 0; i < 8; ++i)
      aA[i] = *(const float4*)(xw + (size_t)(rg + 8 * i) * 256);

    for (int k0 = 0; k0 < 256; k0 += 8) {
#pragma unroll
      for (int i = 0; i < 8; ++i)
        aB[i] = *(const float4*)(xw + (size_t)(rg + 8 * i) * 256 + k0 + 4);
      {
        const int bq = 4 * ((k0 >> 2) ^ mg);
        float4 b4[4];
#pragma unroll
        for (int j = 0; j < 4; ++j)
          b4[j] = *(const float4*)(Bl + (m0 + j) * 256 + bq);
#pragma unroll
        for (int i = 0; i < 8; ++i)
#pragma unroll
          for (int j = 0; j < 4; ++j) {
            acc[i][j] = fmaf(aA[i].x, b4[j].x, acc[i][j]);
            acc[i][j] = fmaf(aA[i].y, b4[j].y, acc[i][j]);
            acc[i][j] = fmaf(aA[i].z, b4[j].z, acc[i][j]);
            acc[i][j] = fmaf(aA[i].w, b4[j].w, acc[i][j]);
          }
      }
      if (k0 + 8 < 256) {
#pragma unroll
        for (int i = 0; i < 8; ++i)
          aA[i] = *(const float4*)(xw + (size_t)(rg + 8 * i) * 256 + k0 + 8);
      }
      {
        const int bq = 4 * (((k0 + 4) >> 2) ^ mg);
        float4 b4[4];
#pragma unroll
        for (int j = 0; j < 4; ++j)
          b4[j] = *(const float4*)(Bl + (m0 + j) * 256 + bq);
#pragma unroll
        for (int i = 0; i < 8; ++i)
#pragma unroll
          for (int j = 0; j < 4; ++j) {
            acc[i][j] = fmaf(aB[i].x, b4[j].x, acc[i][j]);
            acc[i][j] = fmaf(aB[i].y, b4[j].y, acc[i][j]);
            acc[i][j] = fmaf(aB[i].z, b4[j].z, acc[i][j]);
            acc[i][j] = fmaf(aB[i].w, b4[j].w, acc[i][j]);
          }
      }
    }
    float* v = ws + OFF_V;
#pragma unroll
    for (int i = 0; i < 8; ++i)
      *(float4*)(v + (size_t)(rowbase + rg + 8 * i) * 64 + m0) =
          make_float4(acc[i][0], acc[i][1], acc[i][2], acc[i][3]);
  }
}

// ---------------------------------------------------------------------------
// K_chunk: per-WAVE chunk scan, zero barriers in the scan loop.
//   wave w handles chunk c = blockIdx.x*4 + w of batch blockIdx.y.
//   lane r holds AT row r in 64 VGPRs; h broadcast via per-wave LDS hb[64].
//   phase=1: emit final state to S. Extra blocks (x==8): y0=squarings, y1=CP.
//   phase=3: H kept in swizzled LDS (in place over u), fused y-epilogue.
// ---------------------------------------------------------------------------
__global__ __launch_bounds__(256) void k_chunk(float* __restrict__ ws,
                                               const float* __restrict__ Cm,
                                               float* __restrict__ y,
                                               int phase) {
  __shared__ __align__(16) float sh[33024];   // 129 KB
  float* Hs  = sh;            // [4][64][64] swizzled (per-wave chunk u/H)
  float* CPs = sh + 16384;    // [256][64] swizzled (phase 3)
  float* hb  = sh + 32768;    // [4][64]
  const int t = threadIdx.x, w = t >> 6, lane = t & 63;

  if (blockIdx.x == 8) {
    if (blockIdx.y == 0) {
      // ---- squarings: AT^64 -> ws ----
      float* Pa = sh;            // [64][68]
      float* Pb = sh + 4352;
#pragma unroll
      for (int i = 0; i < 4; ++i) {
        int e = 4 * (t + 256 * i);
        int r = e >> 6, c2 = e & 63;
        *(float4*)(Pa + r * 68 + c2) = *(const float4*)(ws + OFF_AT + e);
      }
      __syncthreads();
      mm64(Pb, Pa, Pa, t);   // ^2
      mm64(Pa, Pb, Pb, t);   // ^4
      mm64(Pb, Pa, Pa, t);   // ^8
      mm64(Pa, Pb, Pb, t);   // ^16
      mm64(Pb, Pa, Pa, t);   // ^32
      mm64(Pa, Pb, Pb, t);   // ^64
#pragma unroll
      for (int i = 0; i < 4; ++i) {
        int e = 4 * (t + 256 * i);
        int r = e >> 6, c2 = e & 63;
        *(float4*)(ws + OFF_P64 + e) = *(const float4*)(Pa + r * 68 + c2);
      }
    } else if (blockIdx.y == 1) {
      // ---- CP = 0.1 * C @ Minv -> ws ----
      float* Ms = sh;            // [64][68]
      float* Cs = sh + 4352;     // [64][68]
#pragma unroll
      for (int i = 0; i < 4; ++i) {
        int e = 4 * (t + 256 * i);
        int kk = e >> 6, nn = e & 63;
        *(float4*)(Ms + kk * 68 + nn) = *(const float4*)(ws + OFF_MINV + e);
      }
      __syncthreads();
      const int r0 = 4 * (t >> 4), c0 = 4 * (t & 15);
      for (int ob = 0; ob < 4; ++ob) {
#pragma unroll
        for (int i = 0; i < 4; ++i) {
          int e = 4 * (t + 256 * i);
          int orow = e >> 6, kk = e & 63;
          *(float4*)(Cs + orow * 68 + kk) =
              *(const float4*)(Cm + (size_t)(64 * ob + orow) * 64 + kk);
        }
        __syncthreads();
        float acc[4][4] = {};
        for (int k = 0; k < 64; ++k) {
          float4 bv = *(const float4*)(Ms + k * 68 + c0);
#pragma unroll
          for (int i = 0; i < 4; ++i) {
            float av = Cs[(r0 + i) * 68 + k];
            acc[i][0] = fmaf(av, bv.x, acc[i][0]);
            acc[i][1] = fmaf(av, bv.y, acc[i][1]);
            acc[i][2] = fmaf(av, bv.z, acc[i][2]);
            acc[i][3] = fmaf(av, bv.w, acc[i][3]);
          }
        }
#pragma unroll
        for (int i = 0; i < 4; ++i)
          *(float4*)(ws + OFF_CP + (size_t)(64 * ob + r0 + i) * 64 + c0) =
              make_float4(0.1f * acc[i][0], 0.1f * acc[i][1], 0.1f * acc[i][2],
                          0.1f * acc[i][3]);
        __syncthreads();
      }
    }
    return;
  }

  const int b = blockIdx.y, c = blockIdx.x * 4 + w;
  const int r = lane;

  // AT row r -> registers
  float a[64];
#pragma unroll
  for (int k4 = 0; k4 < 16; ++k4) {
    float4 v4 = *(const float4*)(ws + OFF_AT + r * 64 + 4 * k4);
    a[4 * k4 + 0] = v4.x; a[4 * k4 + 1] = v4.y;
    a[4 * k4 + 2] = v4.z; a[4 * k4 + 3] = v4.w;
  }

  // stage u chunk (row-swizzled) into this wave's Hs
  float* Hw = Hs + w * 4096;
  const float* u = ws + OFF_V + (size_t)(b * LEN + c * CHUNK) * 64;
#pragma unroll
  for (int q = 0; q < 16; ++q) {
    int trow = 4 * q + (lane >> 4);
    int s4 = lane & 15;
    gload16(u + trow * 64 + 4 * (s4 ^ KEYR(trow)), Hw + q * 256, lane * 4);
  }
  if (phase == 3) {
    // stage CP (row-swizzled), whole block covers 64 chunks
#pragma unroll
    for (int q = 0; q < 16; ++q) {
      int qq = 16 * w + q;
      int orow = 4 * qq + (lane >> 4);
      int s4 = lane & 15;
      gload16(ws + OFF_CP + (size_t)orow * 64 + 4 * (s4 ^ KEYR(orow)),
              CPs + qq * 256, lane * 4);
    }
  }
  float h0 = (phase == 3)
                 ? ws[OFF_INST + (size_t)(b * NCHUNK + c) * 64 + r]
                 : 0.0f;
  asm volatile("s_waitcnt vmcnt(0)" ::: "memory");
  float* hw = hb + w * 64;
  hw[r] = h0;
  asm volatile("" ::: "memory");

  // ---- 64 scan steps, barrier-free (wave-synchronous) ----
  float hlast = h0;
  for (int tt = 0; tt < 64; ++tt) {
    float ac0 = 0.f, ac1 = 0.f, ac2 = 0.f, ac3 = 0.f;
#pragma unroll
    for (int k = 0; k < 64; k += 4) {
      float4 hv = *(const float4*)(hw + k);     // broadcast
      ac0 = fmaf(a[k + 0], hv.x, ac0);
      ac1 = fmaf(a[k + 1], hv.y, ac1);
      ac2 = fmaf(a[k + 2], hv.z, ac2);
      ac3 = fmaf(a[k + 3], hv.w, ac3);
    }
    const int slot = tt * 64 + 4 * ((r >> 2) ^ KEYR(tt)) + (r & 3);
    float hn = ((ac0 + ac1) + (ac2 + ac3)) + Hw[slot];
    hw[r] = hn;
    if (phase == 3) Hw[slot] = hn;
    hlast = hn;
    asm volatile("" ::: "memory");
  }

  if (phase != 3) {
    ws[OFF_S + (size_t)(b * NCHUNK + c) * 64 + r] = hlast;
    return;
  }

  // ---- fused y-epilogue: y[64 x 256] = H_chunk @ CP^T ----
  __syncthreads();
  const int rg = lane >> 3, og = lane & 7;
  for (int p = 0; p < 4; ++p) {
    float acc[8][8] = {};
    for (int k0 = 0; k0 < 64; k0 += 4) {
      float4 a4[8], b4[8];
#pragma unroll
      for (int i = 0; i < 8; ++i) {
        int trow = rg + 8 * i;
        a4[i] = *(const float4*)(Hw + trow * 64 + 4 * ((k0 >> 2) ^ KEYR(trow)));
      }
#pragma unroll
      for (int j = 0; j < 8; ++j) {
        int orow = p * 64 + og * 8 + j;
        b4[j] =
            *(const float4*)(CPs + orow * 64 + 4 * ((k0 >> 2) ^ KEYR(orow)));
      }
#pragma unroll
      for (int i = 0; i < 8; ++i)
#pragma unroll
        for (int j = 0; j < 8; ++j) {
          acc[i][j] = fmaf(a4[i].x, b4[j].x, acc[i][j]);
          acc[i][j] = fmaf(a4[i].y, b4[j].y, acc[i][j]);
          acc[i][j] = fmaf(a4[i].z, b4[j].z, acc[i][j]);
          acc[i][j] = fmaf(a4[i].w, b4[j].w, acc[i][j]);
        }
    }
#pragma unroll
    for (int i = 0; i < 8; ++i) {
      float* yp = y + (size_t)(b * LEN + c * CHUNK + rg + 8 * i) * 256 +
                  p * 64 + og * 8;
      *(float4*)(yp) =
          make_float4(acc[i][0], acc[i][1], acc[i][2], acc[i][3]);
      *(float4*)(yp + 4) =
          make_float4(acc[i][4], acc[i][5], acc[i][6], acc[i][7]);
    }
  }
}

// ---------------------------------------------------------------------------
// K_carry: per-WAVE sequential carry per batch (b = blockIdx.x*4 + w):
//   INST[b][0]=0; INST[b][c] = AT64 @ INST[b][c-1] + S[b][c-1]
// ---------------------------------------------------------------------------
__global__ __launch_bounds__(256) void k_carry(float* __restrict__ ws) {
  __shared__ __align__(16) float slds[4][NCHUNK * 64];   // 32 KB
  __shared__ __align__(16) float hbc[4][64];
  const int t = threadIdx.x, w = t >> 6, lane = t & 63;
  const int b = blockIdx.x * 4 + w;
  const int r = lane;
  float a[64];
#pragma unroll
  for (int k4 = 0; k4 < 16; ++k4) {
    float4 v4 = *(const float4*)(ws + OFF_P64 + r * 64 + 4 * k4);
    a[4 * k4 + 0] = v4.x; a[4 * k4 + 1] = v4.y;
    a[4 * k4 + 2] = v4.z; a[4 * k4 + 3] = v4.w;
  }
#pragma unroll
  for (int q = 0; q < 8; ++q)
    gload16(ws + OFF_S + (size_t)b * (NCHUNK * 64) + q * 256 + 4 * lane,
            &slds[w][q * 256], lane * 4);
  ws[OFF_INST + (size_t)b * (NCHUNK * 64) + r] = 0.0f;
  asm volatile("s_waitcnt vmcnt(0)" ::: "memory");
  float* hw = hbc[w];
  hw[r] = 0.0f;
  asm volatile("" ::: "memory");
  for (int cc = 1; cc < NCHUNK; ++cc) {
    float ac0 = 0.f, ac1 = 0.f, ac2 = 0.f, ac3 = 0.f;
#pragma unroll
    for (int k = 0; k < 64; k += 4) {
      float4 hv = *(const float4*)(hw + k);
      ac0 = fmaf(a[k + 0], hv.x, ac0);
      ac1 = fmaf(a[k + 1], hv.y, ac1);
      ac2 = fmaf(a[k + 2], hv.z, ac2);
      ac3 = fmaf(a[k + 3], hv.w, ac3);
    }
    float hn = ((ac0 + ac1) + (ac2 + ac3)) + slds[w][(cc - 1) * 64 + r];
    hw[r] = hn;
    ws[OFF_INST + (size_t)b * (NCHUNK * 64) + cc * 64 + r] = hn;
    asm volatile("" ::: "memory");
  }
}

// ---------------------------------------------------------------------------
extern "C" void kernel_launch(void* const* d_in, const int* in_sizes, int n_in,
                              void* d_out, int out_size, void* d_ws,
                              size_t ws_size, hipStream_t stream) {
  const float* x = (const float*)d_in[0];
  const float* A = (const float*)d_in[1];
  const float* Bm = (const float*)d_in[2];
  const float* Cm = (const float*)d_in[3];
  float* y = (float*)d_out;
  float* ws = (float*)d_ws;
  if (ws_size < (size_t)WS_FLOATS * sizeof(float)) return;  // scratch too small

  hipLaunchKernelGGL(k_fused0, dim3(1 + ROWS / 128), dim3(256), 0, stream, A,
                     Bm, x, ws);
  hipLaunchKernelGGL(k_chunk, dim3(NCHUNK / 4 + 1, B_SZ), dim3(256), 0, stream,
                     ws, Cm, y, 1);
  hipLaunchKernelGGL(k_carry, dim3(B_SZ / 4), dim3(256), 0, stream, ws);
  hipLaunchKernelGGL(k_chunk, dim3(NCHUNK / 4, B_SZ), dim3(256), 0, stream, ws,
                     Cm, y, 3);
}

// Round 5
// 250.220 us; speedup vs baseline: 1.1415x; 1.1415x over previous
//
#include <hip/hip_runtime.h>

#define B_SZ   32
#define LEN    2048
#define DIM    256
#define NST    64
#define OUTD   256
#define CHUNK  32
#define NCHUNK (LEN / CHUNK)     // 64
#define ROWS   (B_SZ * LEN)      // 65536
#define NCID   (B_SZ * NCHUNK)   // 2048 chunks total

// ws layout (float offsets)
#define OFF_AT   0               // A_tilde [64][64]
#define OFF_P32  4096            // A_tilde^32 [64][64]
#define OFF_MINV 8192            // Minv [64][64]
#define OFF_CP   12288           // CP[o][n] = 0.1*(C@Minv), [256][64]
#define OFF_S    28672           // chunk-final states [B][NCHUNK][64]
#define OFF_INST 159744          // chunk carry-in states [B][NCHUNK][64]
#define OFF_V    290816          // v = x @ B^T [ROWS][64]; H in-place
#define WS_FLOATS (OFF_V + (size_t)ROWS * 64)   // 4,485,120 floats = 17.1 MiB

// ---------------------------------------------------------------------------
__device__ __forceinline__ void gload16(const float* gp, float* lds_base,
                                        int lane_off_f) {
#if __has_builtin(__builtin_amdgcn_global_load_lds)
  (void)lane_off_f;
  __builtin_amdgcn_global_load_lds(
      (const __attribute__((address_space(1))) unsigned int*)gp,
      (__attribute__((address_space(3))) unsigned int*)lds_base, 16, 0, 0);
#else
  float4 tmp = *(const float4*)gp;
  *(float4*)(lds_base + lane_off_f) = tmp;
#endif
}

// dst = a @ b, [64][68] LDS tiles, 256 threads, 4x4 reg tiles.
__device__ __forceinline__ void mm64(float* dst, const float* a, const float* b,
                                     int t) {
  const int r0 = 4 * (t >> 4), c0 = 4 * (t & 15);
  float acc[4][4] = {};
  for (int k = 0; k < 64; ++k) {
    float4 bv = *(const float4*)(b + k * 68 + c0);
#pragma unroll
    for (int i = 0; i < 4; ++i) {
      float av = a[(r0 + i) * 68 + k];
      acc[i][0] = fmaf(av, bv.x, acc[i][0]);
      acc[i][1] = fmaf(av, bv.y, acc[i][1]);
      acc[i][2] = fmaf(av, bv.z, acc[i][2]);
      acc[i][3] = fmaf(av, bv.w, acc[i][3]);
    }
  }
  __syncthreads();
#pragma unroll
  for (int i = 0; i < 4; ++i)
    *(float4*)(dst + (r0 + i) * 68 + c0) =
        make_float4(acc[i][0], acc[i][1], acc[i][2], acc[i][3]);
  __syncthreads();
}

// ---------------------------------------------------------------------------
// K_A fused: block 0 = prep: GJ inverse (AT, Minv), 5 squarings (AT^32),
// CP = 0.1*C@Minv.  Blocks 1..1024 = round-0 v-GEMM (64-row tile, 4x4 regs).
// ---------------------------------------------------------------------------
__global__ __launch_bounds__(256) void k_fused0(const float* __restrict__ A,
                                                const float* __restrict__ Bm,
                                                const float* __restrict__ Cm,
                                                const float* __restrict__ x,
                                                float* __restrict__ ws) {
  __shared__ __align__(16) float sh[13056];    // 52.2 KB
  const int t = threadIdx.x;

  if (blockIdx.x == 0) {
    float* Pa = sh;             // [64][68]
    float* Pb = sh + 4352;      // [64][68]
    float* Pc = sh + 8704;      // [64][68] Minv (GJ scratch aliases start)
    float* rbM = Pc;            // [2][64]
    float* rbI = Pc + 128;      // [2][64]
    float* cb  = Pc + 256;      // [2][64]

    const int tc = t & 63;      // column owned
    const int tr = t >> 6;      // 0..3; rows 16*tr+i
    float M[16], Iv[16];
#pragma unroll
    for (int i = 0; i < 16; ++i) {
      int r = 16 * tr + i;
      M[i] = 0.05f * A[r * 64 + tc] + (r == tc ? 1.0f : 0.0f);
      Iv[i] = (r == tc) ? 1.0f : 0.0f;
    }
    if (tr == 0) { rbM[tc] = M[0]; rbI[tc] = Iv[0]; }
    if (tc == 0)
      for (int i = 0; i < 16; ++i) cb[16 * tr + i] = M[i];
    __syncthreads();

    // ---- Gauss-Jordan, no pivoting, 1 barrier/iter ----
#pragma unroll
    for (int k = 0; k < 64; ++k) {
      const int cur = (k & 1) * 64, nxt = ((k + 1) & 1) * 64;
      float rinv = 1.0f / rbM[cur + k];
      float rM = rbM[cur + tc] * rinv;
      float rI = rbI[cur + tc] * rinv;
#pragma unroll
      for (int i = 0; i < 16; ++i) {
        int r = 16 * tr + i;
        if (r == k) { M[i] = rM; Iv[i] = rI; }
        else {
          float f = cb[cur + r];
          M[i] = fmaf(-f, rM, M[i]);
          Iv[i] = fmaf(-f, rI, Iv[i]);
        }
      }
      if (k < 63) {
        if (tr == ((k + 1) >> 4)) {
          rbM[nxt + tc] = M[(k + 1) & 15];
          rbI[nxt + tc] = Iv[(k + 1) & 15];
        }
        if (tc == k + 1)
          for (int i = 0; i < 16; ++i) cb[nxt + 16 * tr + i] = M[i];
      }
      __syncthreads();
    }

    // ---- AT, Minv -> ws; Pa = AT; Pc = Minv ----
#pragma unroll
    for (int i = 0; i < 16; ++i) {
      int r = 16 * tr + i;
      float at = 2.0f * Iv[i] - (r == tc ? 1.0f : 0.0f);
      ws[OFF_AT + r * 64 + tc] = at;
      ws[OFF_MINV + r * 64 + tc] = Iv[i];
      Pa[r * 68 + tc] = at;
      Pc[r * 68 + tc] = Iv[i];
    }
    __syncthreads();

    // ---- 5 squarings -> AT^32 in Pb -> ws ----
    mm64(Pb, Pa, Pa, t);   // ^2
    mm64(Pa, Pb, Pb, t);   // ^4
    mm64(Pb, Pa, Pa, t);   // ^8
    mm64(Pa, Pb, Pb, t);   // ^16
    mm64(Pb, Pa, Pa, t);   // ^32
#pragma unroll
    for (int i = 0; i < 16; ++i) {
      int r = 16 * tr + i;
      ws[OFF_P32 + r * 64 + tc] = Pb[r * 68 + tc];
    }

    // ---- CP = 0.1 * C @ Minv : thread t owns output row o = t ----
    {
      const float* Crow = Cm + (size_t)t * 64;
      float4 acc4[16];
      for (int q = 0; q < 16; ++q) acc4[q] = make_float4(0.f, 0.f, 0.f, 0.f);
      for (int k = 0; k < 64; k += 4) {
        float4 c4 = *(const float4*)(Crow + k);
        float ck[4] = {c4.x, c4.y, c4.z, c4.w};
#pragma unroll
        for (int kk = 0; kk < 4; ++kk) {
          const float* mrow = Pc + (k + kk) * 68;
          float cc = ck[kk];
#pragma unroll
          for (int q = 0; q < 16; ++q) {
            float4 mv = *(const float4*)(mrow + 4 * q);
            acc4[q].x = fmaf(cc, mv.x, acc4[q].x);
            acc4[q].y = fmaf(cc, mv.y, acc4[q].y);
            acc4[q].z = fmaf(cc, mv.z, acc4[q].z);
            acc4[q].w = fmaf(cc, mv.w, acc4[q].w);
          }
        }
      }
      float* cp = ws + OFF_CP + (size_t)t * 64;
      for (int q = 0; q < 16; ++q)
        *(float4*)(cp + 4 * q) =
            make_float4(0.1f * acc4[q].x, 0.1f * acc4[q].y, 0.1f * acc4[q].z,
                        0.1f * acc4[q].w);
    }
  } else {
    // ---- round-0 v-GEMM: v[row][m] = sum_d x[row][d]*B[m][d], 64-row tile --
    float* xsT = sh;            // [64][68]: xsT[dd][rr]
    float* bsT = sh + 4352;     // [64][68]: bsT[dd][m]
    const int rowbase = ((int)blockIdx.x - 1) * 64;
    const int r0 = 4 * (t >> 4), m0 = 4 * (t & 15);
    float acc[4][4] = {};
    for (int db = 0; db < 4; ++db) {
      int d0 = db * 64;
      for (int i = 0; i < 4; ++i) {
        int e = 4 * (t + 256 * i);           // 0..4092
        int rr = e >> 6, dd = e & 63;        // rr: row / m index
        float4 xv = *(const float4*)(x + (size_t)(rowbase + rr) * 256 + d0 + dd);
        xsT[(dd + 0) * 68 + rr] = xv.x;
        xsT[(dd + 1) * 68 + rr] = xv.y;
        xsT[(dd + 2) * 68 + rr] = xv.z;
        xsT[(dd + 3) * 68 + rr] = xv.w;
        float4 bv = *(const float4*)(Bm + (size_t)rr * 256 + d0 + dd);
        bsT[(dd + 0) * 68 + rr] = bv.x;
        bsT[(dd + 1) * 68 + rr] = bv.y;
        bsT[(dd + 2) * 68 + rr] = bv.z;
        bsT[(dd + 3) * 68 + rr] = bv.w;
      }
      __syncthreads();
      for (int k = 0; k < 64; ++k) {
        float4 av4 = *(const float4*)(xsT + k * 68 + r0);
        float4 bv4 = *(const float4*)(bsT + k * 68 + m0);
        float av[4] = {av4.x, av4.y, av4.z, av4.w};
        float bv[4] = {bv4.x, bv4.y, bv4.z, bv4.w};
        for (int i = 0; i < 4; ++i)
          for (int j = 0; j < 4; ++j) acc[i][j] = fmaf(av[i], bv[j], acc[i][j]);
      }
      __syncthreads();
    }
    float* v = ws + OFF_V;
    for (int i = 0; i < 4; ++i)
      *(float4*)(v + (size_t)(rowbase + r0 + i) * 64 + m0) =
          make_float4(acc[i][0], acc[i][1], acc[i][2], acc[i][3]);
  }
}

// ---------------------------------------------------------------------------
// K_chunk: per-WAVE chunk scan (CHUNK=32), barrier-free, high occupancy.
//   wave w of block handles flat chunk cid = blockIdx.x*4+w; b=cid>>6,c=cid&63.
//   lane r holds AT row r in 64 VGPRs; h broadcast via per-wave LDS hb[64].
//   phase=1: emit final state to S.  phase=3: h0=INST, stream h rows to ws
//   (in place over v).
// ---------------------------------------------------------------------------
__global__ __launch_bounds__(256, 4) void k_chunk(float* __restrict__ ws,
                                                  int phase) {
  __shared__ __align__(16) float Hs[4 * CHUNK * 64];   // 32 KB
  __shared__ __align__(16) float hb[4 * 64];
  const int t = threadIdx.x, w = t >> 6, lane = t & 63;
  const int cid = blockIdx.x * 4 + w;
  const int b = cid >> 6, c = cid & (NCHUNK - 1);
  const int r = lane;

  // AT row r -> registers
  float a[64];
#pragma unroll
  for (int k4 = 0; k4 < 16; ++k4) {
    float4 v4 = *(const float4*)(ws + OFF_AT + r * 64 + 4 * k4);
    a[4 * k4 + 0] = v4.x; a[4 * k4 + 1] = v4.y;
    a[4 * k4 + 2] = v4.z; a[4 * k4 + 3] = v4.w;
  }

  // stage u chunk (linear) into this wave's Hs
  float* Hw = Hs + w * (CHUNK * 64);
  const float* u = ws + OFF_V + (size_t)(b * LEN + c * CHUNK) * 64;
#pragma unroll
  for (int q = 0; q < 8; ++q)
    gload16(u + q * 256 + lane * 4, Hw + q * 256, lane * 4);

  float h0 = (phase == 3)
                 ? ws[OFF_INST + (size_t)(b * NCHUNK + c) * 64 + r]
                 : 0.0f;
  asm volatile("s_waitcnt vmcnt(0)" ::: "memory");
  float* hw = hb + w * 64;
  hw[r] = h0;
  asm volatile("" ::: "memory");

  float* hout = ws + OFF_V + (size_t)(b * LEN + c * CHUNK) * 64;
  float hlast = h0;
#pragma unroll 4
  for (int tt = 0; tt < CHUNK; ++tt) {
    float ac0 = 0.f, ac1 = 0.f, ac2 = 0.f, ac3 = 0.f;
#pragma unroll
    for (int k = 0; k < 64; k += 4) {
      float4 hv = *(const float4*)(hw + k);     // broadcast (uniform addr)
      ac0 = fmaf(a[k + 0], hv.x, ac0);
      ac1 = fmaf(a[k + 1], hv.y, ac1);
      ac2 = fmaf(a[k + 2], hv.z, ac2);
      ac3 = fmaf(a[k + 3], hv.w, ac3);
    }
    float hn = ((ac0 + ac1) + (ac2 + ac3)) + Hw[tt * 64 + r];
    hw[r] = hn;
    if (phase == 3) hout[(size_t)tt * 64 + r] = hn;   // fire-and-forget
    hlast = hn;
    asm volatile("" ::: "memory");
  }
  if (phase != 3) ws[OFF_S + (size_t)(b * NCHUNK + c) * 64 + r] = hlast;
}

// ---------------------------------------------------------------------------
// K_carry: per-WAVE sequential carry per batch (b = blockIdx.x*4 + w):
//   INST[b][0]=0; INST[b][c] = AT32 @ INST[b][c-1] + S[b][c-1]
// ---------------------------------------------------------------------------
__global__ __launch_bounds__(256) void k_carry(float* __restrict__ ws) {
  __shared__ __align__(16) float hbc[4][64];
  const int t = threadIdx.x, w = t >> 6, lane = t & 63;
  const int b = blockIdx.x * 4 + w;
  const int r = lane;
  float a[64];
#pragma unroll
  for (int k4 = 0; k4 < 16; ++k4) {
    float4 v4 = *(const float4*)(ws + OFF_P32 + r * 64 + 4 * k4);
    a[4 * k4 + 0] = v4.x; a[4 * k4 + 1] = v4.y;
    a[4 * k4 + 2] = v4.z; a[4 * k4 + 3] = v4.w;
  }
  const float* S = ws + OFF_S + (size_t)b * (NCHUNK * 64);
  float* INST = ws + OFF_INST + (size_t)b * (NCHUNK * 64);
  INST[r] = 0.0f;
  float* hw = hbc[w];
  hw[r] = 0.0f;
  float s_pre = S[r];                       // S[b][0][r]
  asm volatile("" ::: "memory");
  for (int cc = 1; cc < NCHUNK; ++cc) {
    float s_nxt = (cc < NCHUNK - 1) ? S[(size_t)cc * 64 + r] : 0.0f;
    float ac0 = 0.f, ac1 = 0.f, ac2 = 0.f, ac3 = 0.f;
#pragma unroll
    for (int k = 0; k < 64; k += 4) {
      float4 hv = *(const float4*)(hw + k);
      ac0 = fmaf(a[k + 0], hv.x, ac0);
      ac1 = fmaf(a[k + 1], hv.y, ac1);
      ac2 = fmaf(a[k + 2], hv.z, ac2);
      ac3 = fmaf(a[k + 3], hv.w, ac3);
    }
    float hn = ((ac0 + ac1) + (ac2 + ac3)) + s_pre;
    hw[r] = hn;
    INST[(size_t)cc * 64 + r] = hn;
    s_pre = s_nxt;
    asm volatile("" ::: "memory");
  }
}

// ---------------------------------------------------------------------------
// K7: y[row][o] = sum_n h[row][n] * CP[o][n]  (64-row x 64-o tile per wg)
// ---------------------------------------------------------------------------
__global__ __launch_bounds__(256) void k_ygemm(const float* __restrict__ ws,
                                               float* __restrict__ y) {
  __shared__ __align__(16) float hs[64 * 68];
  __shared__ __align__(16) float cs[64 * 68];
  const int t = threadIdx.x;
  const int rowbase = blockIdx.x * 64;
  const int o0 = blockIdx.y * 64;
  const float* h = ws + OFF_V;
  const float* CP = ws + OFF_CP;
  for (int i = 0; i < 4; ++i) {
    int e = 4 * (t + 256 * i);
    int rr = e >> 6, nn = e & 63;
    *(float4*)(hs + rr * 68 + nn) =
        *(const float4*)(h + (size_t)rowbase * 64 + e);
    float4 cv = *(const float4*)(CP + (size_t)(o0 + rr) * 64 + nn);
    cs[(nn + 0) * 68 + rr] = cv.x;     // transposed: cs[n][o']
    cs[(nn + 1) * 68 + rr] = cv.y;
    cs[(nn + 2) * 68 + rr] = cv.z;
    cs[(nn + 3) * 68 + rr] = cv.w;
  }
  __syncthreads();
  const int tr = t >> 4, tc = t & 15;
  const int r0 = tr * 4, c0 = tc * 4;
  float acc[4][4] = {};
  for (int k = 0; k < 64; ++k) {
    float4 cv4 = *(const float4*)(cs + k * 68 + c0);
    float cv[4] = {cv4.x, cv4.y, cv4.z, cv4.w};
    for (int i = 0; i < 4; ++i) {
      float hv = hs[(r0 + i) * 68 + k];
      for (int j = 0; j < 4; ++j) acc[i][j] = fmaf(hv, cv[j], acc[i][j]);
    }
  }
  for (int i = 0; i < 4; ++i)
    *(float4*)(y + (size_t)(rowbase + r0 + i) * 256 + o0 + c0) =
        make_float4(acc[i][0], acc[i][1], acc[i][2], acc[i][3]);
}

// ---------------------------------------------------------------------------
extern "C" void kernel_launch(void* const* d_in, const int* in_sizes, int n_in,
                              void* d_out, int out_size, void* d_ws,
                              size_t ws_size, hipStream_t stream) {
  const float* x = (const float*)d_in[0];
  const float* A = (const float*)d_in[1];
  const float* Bm = (const float*)d_in[2];
  const float* Cm = (const float*)d_in[3];
  float* y = (float*)d_out;
  float* ws = (float*)d_ws;
  if (ws_size < (size_t)WS_FLOATS * sizeof(float)) return;  // scratch too small

  hipLaunchKernelGGL(k_fused0, dim3(1 + ROWS / 64), dim3(256), 0, stream, A,
                     Bm, Cm, x, ws);
  hipLaunchKernelGGL(k_chunk, dim3(NCID / 4), dim3(256), 0, stream, ws, 1);
  hipLaunchKernelGGL(k_carry, dim3(B_SZ / 4), dim3(256), 0, stream, ws);
  hipLaunchKernelGGL(k_chunk, dim3(NCID / 4), dim3(256), 0, stream, ws, 3);
  hipLaunchKernelGGL(k_ygemm, dim3(ROWS / 64, OUTD / 64), dim3(256), 0, stream,
                     ws, y);
}

// Round 6
// 217.025 us; speedup vs baseline: 1.3161x; 1.1530x over previous
//
#include <hip/hip_runtime.h>

#define B_SZ   32
#define LEN    2048
#define DIM    256
#define NST    64
#define OUTD   256
#define CHUNK  32
#define NCHUNK (LEN / CHUNK)     // 64
#define ROWS   (B_SZ * LEN)      // 65536
#define NCID   (B_SZ * NCHUNK)   // 2048 chunks total

// ws layout (float offsets)
#define OFF_AT   0               // A_tilde [64][64]
#define OFF_P32  4096            // A_tilde^32 [64][64]
#define OFF_MINV 8192            // Minv [64][64]
#define OFF_CP   12288           // CP[o][n] = 0.1*(C@Minv), [256][64] fp32
#define OFF_S    28672           // chunk-final states [B][NCHUNK][64]
#define OFF_INST 159744          // chunk carry-in states [B][NCHUNK][64]
#define OFF_V    290816          // v = x @ B^T [ROWS][64]; H in-place
#define WS_FLOATS (OFF_V + (size_t)ROWS * 64)   // 17.1 MiB

typedef __attribute__((ext_vector_type(8))) short bf16x8;
typedef __attribute__((ext_vector_type(4))) float f32x4;
union U4 { uint4 u; bf16x8 b; };

// ---------------------------------------------------------------------------
__device__ __forceinline__ void gload16(const float* gp, float* lds_base,
                                        int lane_off_f) {
#if __has_builtin(__builtin_amdgcn_global_load_lds)
  (void)lane_off_f;
  __builtin_amdgcn_global_load_lds(
      (const __attribute__((address_space(1))) unsigned int*)gp,
      (__attribute__((address_space(3))) unsigned int*)lds_base, 16, 0, 0);
#else
  float4 tmp = *(const float4*)gp;
  *(float4*)(lds_base + lane_off_f) = tmp;
#endif
}

// split 8 fp32 (two float4) into bf16x8 hi (truncated) and bf16x8 lo (residual)
__device__ __forceinline__ void split8(float4 a, float4 b, uint4& h, uint4& l) {
  unsigned int ua0 = __float_as_uint(a.x), ua1 = __float_as_uint(a.y);
  unsigned int ua2 = __float_as_uint(a.z), ua3 = __float_as_uint(a.w);
  unsigned int ub0 = __float_as_uint(b.x), ub1 = __float_as_uint(b.y);
  unsigned int ub2 = __float_as_uint(b.z), ub3 = __float_as_uint(b.w);
  h.x = (ua0 >> 16) | (ua1 & 0xFFFF0000u);
  h.y = (ua2 >> 16) | (ua3 & 0xFFFF0000u);
  h.z = (ub0 >> 16) | (ub1 & 0xFFFF0000u);
  h.w = (ub2 >> 16) | (ub3 & 0xFFFF0000u);
  float l0 = a.x - __uint_as_float(ua0 & 0xFFFF0000u);
  float l1 = a.y - __uint_as_float(ua1 & 0xFFFF0000u);
  float l2 = a.z - __uint_as_float(ua2 & 0xFFFF0000u);
  float l3 = a.w - __uint_as_float(ua3 & 0xFFFF0000u);
  float l4 = b.x - __uint_as_float(ub0 & 0xFFFF0000u);
  float l5 = b.y - __uint_as_float(ub1 & 0xFFFF0000u);
  float l6 = b.z - __uint_as_float(ub2 & 0xFFFF0000u);
  float l7 = b.w - __uint_as_float(ub3 & 0xFFFF0000u);
  l.x = (__float_as_uint(l0) >> 16) | (__float_as_uint(l1) & 0xFFFF0000u);
  l.y = (__float_as_uint(l2) >> 16) | (__float_as_uint(l3) & 0xFFFF0000u);
  l.z = (__float_as_uint(l4) >> 16) | (__float_as_uint(l5) & 0xFFFF0000u);
  l.w = (__float_as_uint(l6) >> 16) | (__float_as_uint(l7) & 0xFFFF0000u);
}

// dst = a @ b, [64][68] LDS tiles, 256 threads, 4x4 reg tiles.
__device__ __forceinline__ void mm64(float* dst, const float* a, const float* b,
                                     int t) {
  const int r0 = 4 * (t >> 4), c0 = 4 * (t & 15);
  float acc[4][4] = {};
  for (int k = 0; k < 64; ++k) {
    float4 bv = *(const float4*)(b + k * 68 + c0);
#pragma unroll
    for (int i = 0; i < 4; ++i) {
      float av = a[(r0 + i) * 68 + k];
      acc[i][0] = fmaf(av, bv.x, acc[i][0]);
      acc[i][1] = fmaf(av, bv.y, acc[i][1]);
      acc[i][2] = fmaf(av, bv.z, acc[i][2]);
      acc[i][3] = fmaf(av, bv.w, acc[i][3]);
    }
  }
  __syncthreads();
#pragma unroll
  for (int i = 0; i < 4; ++i)
    *(float4*)(dst + (r0 + i) * 68 + c0) =
        make_float4(acc[i][0], acc[i][1], acc[i][2], acc[i][3]);
  __syncthreads();
}

// ---------------------------------------------------------------------------
// K_A fused: block 0 = GJ inverse only (AT, Minv -> ws).
// Blocks 1..1024 = MFMA v-GEMM: 64 rows/block (16/wave), split-bf16 3-term.
// B staged fp32 in LDS [64][256], 16B-unit swizzle u' = u ^ (n&7).
// ---------------------------------------------------------------------------
__global__ __launch_bounds__(256) void k_fused0(const float* __restrict__ A,
                                                const float* __restrict__ Bm,
                                                const float* __restrict__ x,
                                                float* __restrict__ ws) {
  __shared__ __align__(16) float sh[16384];    // 64 KB
  const int t = threadIdx.x;

  if (blockIdx.x == 0) {
    float* rbM = sh;            // [2][64]
    float* rbI = sh + 128;      // [2][64]
    float* cb  = sh + 256;      // [2][64]
    const int tc = t & 63;
    const int tr = t >> 6;
    float M[16], Iv[16];
#pragma unroll
    for (int i = 0; i < 16; ++i) {
      int r = 16 * tr + i;
      M[i] = 0.05f * A[r * 64 + tc] + (r == tc ? 1.0f : 0.0f);
      Iv[i] = (r == tc) ? 1.0f : 0.0f;
    }
    if (tr == 0) { rbM[tc] = M[0]; rbI[tc] = Iv[0]; }
    if (tc == 0)
      for (int i = 0; i < 16; ++i) cb[16 * tr + i] = M[i];
    __syncthreads();
#pragma unroll
    for (int k = 0; k < 64; ++k) {
      const int cur = (k & 1) * 64, nxt = ((k + 1) & 1) * 64;
      float rinv = 1.0f / rbM[cur + k];
      float rM = rbM[cur + tc] * rinv;
      float rI = rbI[cur + tc] * rinv;
#pragma unroll
      for (int i = 0; i < 16; ++i) {
        int r = 16 * tr + i;
        if (r == k) { M[i] = rM; Iv[i] = rI; }
        else {
          float f = cb[cur + r];
          M[i] = fmaf(-f, rM, M[i]);
          Iv[i] = fmaf(-f, rI, Iv[i]);
        }
      }
      if (k < 63) {
        if (tr == ((k + 1) >> 4)) {
          rbM[nxt + tc] = M[(k + 1) & 15];
          rbI[nxt + tc] = Iv[(k + 1) & 15];
        }
        if (tc == k + 1)
          for (int i = 0; i < 16; ++i) cb[nxt + 16 * tr + i] = M[i];
      }
      __syncthreads();
    }
#pragma unroll
    for (int i = 0; i < 16; ++i) {
      int r = 16 * tr + i;
      ws[OFF_AT + r * 64 + tc] = 2.0f * Iv[i] - (r == tc ? 1.0f : 0.0f);
      ws[OFF_MINV + r * 64 + tc] = Iv[i];
    }
  } else {
    // ---- MFMA v-GEMM ----
    float* Bl = sh;                       // [64][256] fp32, unit-swizzled
    const int w = t >> 6, lane = t & 63;
    // stage B: wave-instr c2 stages full row n = 16w + c2 (1 KB)
#pragma unroll
    for (int c2 = 0; c2 < 16; ++c2) {
      int n = 16 * w + c2;
      const float* gp = Bm + (size_t)n * 256 + 4 * (lane ^ (n & 7));
      gload16(gp, Bl + n * 256, lane * 4);
    }
    __syncthreads();

    const int rowbase = ((int)blockIdx.x - 1) * 64 + 16 * w;
    const int rr = lane & 15, kb = lane >> 4, key = lane & 7;
    const float* xp = x + (size_t)(rowbase + rr) * 256 + 8 * kb;
    f32x4 acc[4] = {{0.f,0.f,0.f,0.f},{0.f,0.f,0.f,0.f},
                    {0.f,0.f,0.f,0.f},{0.f,0.f,0.f,0.f}};
    float4 xc0 = *(const float4*)(xp);
    float4 xc1 = *(const float4*)(xp + 4);
#pragma unroll
    for (int ki = 0; ki < 8; ++ki) {
      float4 xn0, xn1;
      if (ki < 7) {
        xn0 = *(const float4*)(xp + 32 * (ki + 1));
        xn1 = *(const float4*)(xp + 32 * (ki + 1) + 4);
      }
      U4 ah, al;
      split8(xc0, xc1, ah.u, al.u);
#pragma unroll
      for (int nt = 0; nt < 4; ++nt) {
        const float* brow = Bl + (nt * 16 + rr) * 256;
        int U0 = 8 * ki + 2 * kb;
        float4 b0 = *(const float4*)(brow + 4 * (U0 ^ key));
        float4 b1 = *(const float4*)(brow + 4 * ((U0 + 1) ^ key));
        U4 bh, bl2;
        split8(b0, b1, bh.u, bl2.u);
        acc[nt] = __builtin_amdgcn_mfma_f32_16x16x32_bf16(ah.b, bh.b, acc[nt], 0, 0, 0);
        acc[nt] = __builtin_amdgcn_mfma_f32_16x16x32_bf16(al.b, bh.b, acc[nt], 0, 0, 0);
        acc[nt] = __builtin_amdgcn_mfma_f32_16x16x32_bf16(ah.b, bl2.b, acc[nt], 0, 0, 0);
      }
      if (ki < 7) { xc0 = xn0; xc1 = xn1; }
    }
    // D layout: col = lane&15, row = 4*(lane>>4) + reg
    float* v = ws + OFF_V;
#pragma unroll
    for (int nt = 0; nt < 4; ++nt)
#pragma unroll
      for (int j = 0; j < 4; ++j)
        v[(size_t)(rowbase + 4 * kb + j) * 64 + nt * 16 + rr] = acc[nt][j];
  }
}

// ---------------------------------------------------------------------------
// K_chunk: per-WAVE chunk scan (CHUNK=32), barrier-free, high occupancy.
//   phase=1 extra blocks: bx==NCID/4 -> squarings (AT^32); bx==NCID/4+1 -> CP.
// ---------------------------------------------------------------------------
__global__ __launch_bounds__(256, 4) void k_chunk(float* __restrict__ ws,
                                                  const float* __restrict__ Cm,
                                                  int phase) {
  __shared__ __align__(16) float sh[8704];     // 34.8 KB
  float* Hs = sh;            // [4][32][64]
  float* hb = sh + 8192;     // [4][64]
  const int t = threadIdx.x, w = t >> 6, lane = t & 63;

  if (blockIdx.x >= NCID / 4) {
    if (phase != 1) return;
    if (blockIdx.x == NCID / 4) {
      // ---- squarings: AT^32 -> ws ----
      float* Pa = sh;            // [64][68]
      float* Pb = sh + 4352;
#pragma unroll
      for (int i = 0; i < 4; ++i) {
        int e = 4 * (t + 256 * i);
        int r = e >> 6, c2 = e & 63;
        *(float4*)(Pa + r * 68 + c2) = *(const float4*)(ws + OFF_AT + e);
      }
      __syncthreads();
      mm64(Pb, Pa, Pa, t);   // ^2
      mm64(Pa, Pb, Pb, t);   // ^4
      mm64(Pb, Pa, Pa, t);   // ^8
      mm64(Pa, Pb, Pb, t);   // ^16
      mm64(Pb, Pa, Pa, t);   // ^32
#pragma unroll
      for (int i = 0; i < 4; ++i) {
        int e = 4 * (t + 256 * i);
        int r = e >> 6, c2 = e & 63;
        *(float4*)(ws + OFF_P32 + e) = *(const float4*)(Pb + r * 68 + c2);
      }
    } else {
      // ---- CP = 0.1 * C @ Minv -> ws (fp32) ----
      float* Ms = sh;            // [64][68]
      float* Cs = sh + 4352;     // [64][68]
#pragma unroll
      for (int i = 0; i < 4; ++i) {
        int e = 4 * (t + 256 * i);
        int kk = e >> 6, nn = e & 63;
        *(float4*)(Ms + kk * 68 + nn) = *(const float4*)(ws + OFF_MINV + e);
      }
      __syncthreads();
      const int r0 = 4 * (t >> 4), c0 = 4 * (t & 15);
      for (int ob = 0; ob < 4; ++ob) {
#pragma unroll
        for (int i = 0; i < 4; ++i) {
          int e = 4 * (t + 256 * i);
          int orow = e >> 6, kk = e & 63;
          *(float4*)(Cs + orow * 68 + kk) =
              *(const float4*)(Cm + (size_t)(64 * ob + orow) * 64 + kk);
        }
        __syncthreads();
        float acc[4][4] = {};
        for (int k = 0; k < 64; ++k) {
          float4 bv = *(const float4*)(Ms + k * 68 + c0);
#pragma unroll
          for (int i = 0; i < 4; ++i) {
            float av = Cs[(r0 + i) * 68 + k];
            acc[i][0] = fmaf(av, bv.x, acc[i][0]);
            acc[i][1] = fmaf(av, bv.y, acc[i][1]);
            acc[i][2] = fmaf(av, bv.z, acc[i][2]);
            acc[i][3] = fmaf(av, bv.w, acc[i][3]);
          }
        }
#pragma unroll
        for (int i = 0; i < 4; ++i)
          *(float4*)(ws + OFF_CP + (size_t)(64 * ob + r0 + i) * 64 + c0) =
              make_float4(0.1f * acc[i][0], 0.1f * acc[i][1], 0.1f * acc[i][2],
                          0.1f * acc[i][3]);
        __syncthreads();
      }
    }
    return;
  }

  const int cid = blockIdx.x * 4 + w;
  const int b = cid >> 6, c = cid & (NCHUNK - 1);
  const int r = lane;

  float a[64];
#pragma unroll
  for (int k4 = 0; k4 < 16; ++k4) {
    float4 v4 = *(const float4*)(ws + OFF_AT + r * 64 + 4 * k4);
    a[4 * k4 + 0] = v4.x; a[4 * k4 + 1] = v4.y;
    a[4 * k4 + 2] = v4.z; a[4 * k4 + 3] = v4.w;
  }

  float* Hw = Hs + w * (CHUNK * 64);
  const float* u = ws + OFF_V + (size_t)(b * LEN + c * CHUNK) * 64;
#pragma unroll
  for (int q = 0; q < 8; ++q)
    gload16(u + q * 256 + lane * 4, Hw + q * 256, lane * 4);

  float h0 = (phase == 3)
                 ? ws[OFF_INST + (size_t)(b * NCHUNK + c) * 64 + r]
                 : 0.0f;
  asm volatile("s_waitcnt vmcnt(0)" ::: "memory");
  float* hw = hb + w * 64;
  hw[r] = h0;
  asm volatile("" ::: "memory");

  float* hout = ws + OFF_V + (size_t)(b * LEN + c * CHUNK) * 64;
  float hlast = h0;
#pragma unroll 4
  for (int tt = 0; tt < CHUNK; ++tt) {
    float ac0 = 0.f, ac1 = 0.f, ac2 = 0.f, ac3 = 0.f;
#pragma unroll
    for (int k = 0; k < 64; k += 4) {
      float4 hv = *(const float4*)(hw + k);     // broadcast (uniform addr)
      ac0 = fmaf(a[k + 0], hv.x, ac0);
      ac1 = fmaf(a[k + 1], hv.y, ac1);
      ac2 = fmaf(a[k + 2], hv.z, ac2);
      ac3 = fmaf(a[k + 3], hv.w, ac3);
    }
    float hn = ((ac0 + ac1) + (ac2 + ac3)) + Hw[tt * 64 + r];
    hw[r] = hn;
    if (phase == 3) hout[(size_t)tt * 64 + r] = hn;   // fire-and-forget
    hlast = hn;
    asm volatile("" ::: "memory");
  }
  if (phase != 3) ws[OFF_S + (size_t)(b * NCHUNK + c) * 64 + r] = hlast;
}

// ---------------------------------------------------------------------------
// K_carry: per-WAVE sequential carry per batch (b = blockIdx.x*4 + w):
//   INST[b][0]=0; INST[b][c] = AT32 @ INST[b][c-1] + S[b][c-1]
// ---------------------------------------------------------------------------
__global__ __launch_bounds__(256) void k_carry(float* __restrict__ ws) {
  __shared__ __align__(16) float hbc[4][64];
  const int t = threadIdx.x, w = t >> 6, lane = t & 63;
  const int b = blockIdx.x * 4 + w;
  const int r = lane;
  float a[64];
#pragma unroll
  for (int k4 = 0; k4 < 16; ++k4) {
    float4 v4 = *(const float4*)(ws + OFF_P32 + r * 64 + 4 * k4);
    a[4 * k4 + 0] = v4.x; a[4 * k4 + 1] = v4.y;
    a[4 * k4 + 2] = v4.z; a[4 * k4 + 3] = v4.w;
  }
  const float* S = ws + OFF_S + (size_t)b * (NCHUNK * 64);
  float* INST = ws + OFF_INST + (size_t)b * (NCHUNK * 64);
  INST[r] = 0.0f;
  float* hw = hbc[w];
  hw[r] = 0.0f;
  float s_pre = S[r];
  asm volatile("" ::: "memory");
  for (int cc = 1; cc < NCHUNK; ++cc) {
    float s_nxt = (cc < NCHUNK - 1) ? S[(size_t)cc * 64 + r] : 0.0f;
    float ac0 = 0.f, ac1 = 0.f, ac2 = 0.f, ac3 = 0.f;
#pragma unroll
    for (int k = 0; k < 64; k += 4) {
      float4 hv = *(const float4*)(hw + k);
      ac0 = fmaf(a[k + 0], hv.x, ac0);
      ac1 = fmaf(a[k + 1], hv.y, ac1);
      ac2 = fmaf(a[k + 2], hv.z, ac2);
      ac3 = fmaf(a[k + 3], hv.w, ac3);
    }
    float hn = ((ac0 + ac1) + (ac2 + ac3)) + s_pre;
    hw[r] = hn;
    INST[(size_t)cc * 64 + r] = hn;
    s_pre = s_nxt;
    asm volatile("" ::: "memory");
  }
}

// ---------------------------------------------------------------------------
// K_ygemm (MFMA): y[ROWS][256] = h[ROWS][64] @ CP^T, split-bf16 3-term.
// CP staged fp32 in LDS [256][64], 16B-unit swizzle u' = u ^ (o&7), via
// gload16 with pre-swizzled source. 64 rows/block (16/wave), full 256 o.
// ---------------------------------------------------------------------------
__global__ __launch_bounds__(256) void k_ygemm(const float* __restrict__ ws,
                                               float* __restrict__ y) {
  __shared__ __align__(16) float CPl[256 * 64];   // 64 KB
  const int t = threadIdx.x, w = t >> 6, lane = t & 63;
  // stage: wave-instr covers 4 rows (64 slots of 16B)
#pragma unroll
  for (int c2 = 0; c2 < 16; ++c2) {
    int s0 = (w * 16 + c2) * 64;
    int o = (s0 + lane) >> 4, up = lane & 15;
    const float* gp = ws + OFF_CP + (size_t)o * 64 + 4 * (up ^ (o & 7));
    gload16(gp, CPl + s0 * 4, lane * 4);
  }
  __syncthreads();

  const int rowbase = blockIdx.x * 64 + 16 * w;
  const int rr = lane & 15, kb = lane >> 4, key = lane & 7;
  const float* hp = ws + OFF_V + (size_t)(rowbase + rr) * 64 + 8 * kb;
  float4 h0a = *(const float4*)(hp);
  float4 h0b = *(const float4*)(hp + 4);
  float4 h1a = *(const float4*)(hp + 32);
  float4 h1b = *(const float4*)(hp + 36);
  U4 ah0, al0, ah1, al1;
  split8(h0a, h0b, ah0.u, al0.u);
  split8(h1a, h1b, ah1.u, al1.u);

  f32x4 acc[16];
#pragma unroll
  for (int nt = 0; nt < 16; ++nt) acc[nt] = (f32x4){0.f, 0.f, 0.f, 0.f};

#pragma unroll
  for (int nt = 0; nt < 16; ++nt) {
    const float* crow = CPl + (nt * 16 + rr) * 64;
    // ki = 0
    int U0 = 2 * kb;
    float4 b0 = *(const float4*)(crow + 4 * (U0 ^ key));
    float4 b1 = *(const float4*)(crow + 4 * ((U0 + 1) ^ key));
    U4 bh, bl2;
    split8(b0, b1, bh.u, bl2.u);
    acc[nt] = __builtin_amdgcn_mfma_f32_16x16x32_bf16(ah0.b, bh.b, acc[nt], 0, 0, 0);
    acc[nt] = __builtin_amdgcn_mfma_f32_16x16x32_bf16(al0.b, bh.b, acc[nt], 0, 0, 0);
    acc[nt] = __builtin_amdgcn_mfma_f32_16x16x32_bf16(ah0.b, bl2.b, acc[nt], 0, 0, 0);
    // ki = 1
    U0 = 8 + 2 * kb;
    b0 = *(const float4*)(crow + 4 * (U0 ^ key));
    b1 = *(const float4*)(crow + 4 * ((U0 + 1) ^ key));
    split8(b0, b1, bh.u, bl2.u);
    acc[nt] = __builtin_amdgcn_mfma_f32_16x16x32_bf16(ah1.b, bh.b, acc[nt], 0, 0, 0);
    acc[nt] = __builtin_amdgcn_mfma_f32_16x16x32_bf16(al1.b, bh.b, acc[nt], 0, 0, 0);
    acc[nt] = __builtin_amdgcn_mfma_f32_16x16x32_bf16(ah1.b, bl2.b, acc[nt], 0, 0, 0);
  }
#pragma unroll
  for (int nt = 0; nt < 16; ++nt)
#pragma unroll
    for (int j = 0; j < 4; ++j)
      y[(size_t)(rowbase + 4 * kb + j) * 256 + nt * 16 + rr] = acc[nt][j];
}

// ---------------------------------------------------------------------------
extern "C" void kernel_launch(void* const* d_in, const int* in_sizes, int n_in,
                              void* d_out, int out_size, void* d_ws,
                              size_t ws_size, hipStream_t stream) {
  const float* x = (const float*)d_in[0];
  const float* A = (const float*)d_in[1];
  const float* Bm = (const float*)d_in[2];
  const float* Cm = (const float*)d_in[3];
  float* y = (float*)d_out;
  float* ws = (float*)d_ws;
  if (ws_size < (size_t)WS_FLOATS * sizeof(float)) return;  // scratch too small

  hipLaunchKernelGGL(k_fused0, dim3(1 + ROWS / 64), dim3(256), 0, stream, A,
                     Bm, x, ws);
  hipLaunchKernelGGL(k_chunk, dim3(NCID / 4 + 2), dim3(256), 0, stream, ws, Cm, 1);
  hipLaunchKernelGGL(k_carry, dim3(B_SZ / 4), dim3(256), 0, stream, ws);
  hipLaunchKernelGGL(k_chunk, dim3(NCID / 4), dim3(256), 0, stream, ws, Cm, 3);
  hipLaunchKernelGGL(k_ygemm, dim3(ROWS / 64), dim3(256), 0, stream, ws, y);
}